// Round 5
// baseline (170.896 us; speedup 1.0000x reference)
//
#include <hip/hip_runtime.h>
#include <stdint.h>

// BlockLinear: out = block_diag(blocks) @ inp + bias
//   inp (2048,8192), blocks (8,256,256), bias (2048,)
// R7: (a) main = R6 with prefetch distance 3 (three buffer parities; loads for
//     s+3 issued as s is consumed -> issue-to-use ~2-3 loop bodies, covers
//     500-900cy L3/HBM latency). R6 counters showed clean traffic (FETCH 34 MB
//     = L3-resident input, WRITE 66 MB ideal) with 85% stall -> latency-bound,
//     window too shallow. (b) bl_probe diagnostic dispatch before main (output
//     overwritten by main): coalesced reads + EXACT epilogue store pattern, no
//     compute -> measures the access-pattern memory ceiling directly in rocprof.

#define BCOLS 8192

typedef __attribute__((ext_vector_type(8))) short short8;            // 8 bf16
typedef __attribute__((ext_vector_type(4))) float f32x4;             // MFMA acc
typedef __attribute__((ext_vector_type(4))) unsigned short ushort4v; // 8 B store

__device__ __forceinline__ unsigned short f2bf(float x) {
  unsigned u = __builtin_bit_cast(unsigned, x);
  u += 0x7FFFu + ((u >> 16) & 1u);  // RNE
  return (unsigned short)(u >> 16);
}
__device__ __forceinline__ float bf2f(unsigned short h) {
  unsigned u = ((unsigned)h) << 16;
  return __builtin_bit_cast(float, u);
}
__device__ __forceinline__ unsigned pk2(float a, float b) {
  return (unsigned)f2bf(a) | ((unsigned)f2bf(b) << 16);
}

// bf16 data: bits[8:15] of each dword = sign|exp byte clustered in [0x3B,0x43]
// for N(0,1); fp32: uniform mantissa bits. 32-sample vote, wave-uniform.
__device__ __forceinline__ bool detect_bf16(const void* p) {
  const unsigned* u = (const unsigned*)p;
  int votes = 0;
#pragma unroll
  for (int i = 0; i < 32; ++i) {
    unsigned b = (u[i] >> 8) & 0x7Fu;
    votes += (b >= 0x3Bu && b <= 0x43u) ? 1 : 0;
  }
  return votes >= 16;
}

// Pre-pass: blocks (any dtype) -> bf16 copy in d_ws. 524288 elems, 4/thread.
__global__ void bl_convw(const void* __restrict__ blocks,
                         unsigned short* __restrict__ wbf) {
  const int i = blockIdx.x * 256 + threadIdx.x;
  if (detect_bf16(blocks)) {
    ((ushort4v*)wbf)[i] = ((const ushort4v*)blocks)[i];
  } else {
    float4 v = ((const float4*)blocks)[i];
    ushort4v p = {f2bf(v.x), f2bf(v.y), f2bf(v.z), f2bf(v.w)};
    ((ushort4v*)wbf)[i] = p;
  }
}

// ---------------- diagnostic probe: pattern ceiling, no compute ----------------
// Same wg mapping as main (kb=wg&7, b0=(wg>>3)<<6). Reads the wg's input tile
// with clean coalesced uint4 loads; stores garbage in the main kernel's EXACT
// epilogue pattern. Output is overwritten by the main kernel afterwards.
template <typename T>
__device__ __forceinline__ void run_diag(const T* __restrict__ inp,
                                         T* __restrict__ out) {
  constexpr bool BF = (sizeof(T) == 2);
  const int t    = threadIdx.x;
  const int wg   = blockIdx.x;
  const int kb   = wg & 7;
  const int b0   = (wg >> 3) << 6;
  const int lane = t & 63;
  const int cc   = lane & 15;
  const int qq   = lane >> 4;
  const int m0   = (t >> 6) << 6;

  const char* base = (const char*)(inp + (size_t)(kb * 256) * BCOLS + b0);
  const int rowt = t >> 4;                       // 16 row-groups
  const int colb = BF ? (t & 7) * 16 : (t & 15) * 16;  // stay inside tile row
  uint4 v[8];
#pragma unroll
  for (int r = 0; r < 8; ++r)
    v[r] = *(const uint4*)(base + (size_t)(rowt + r * 16) * BCOLS * sizeof(T) + colb);
  unsigned sx = 0;
#pragma unroll
  for (int r = 0; r < 8; ++r) sx += v[r].x + v[r].y + v[r].z + v[r].w;

  const int mrow0 = kb * 256 + m0;
#pragma unroll
  for (int mt = 0; mt < 4; ++mt) {
    const size_t rowoff = (size_t)(mrow0 + mt * 16 + cc) * BCOLS;
#pragma unroll
    for (int bt = 0; bt < 4; ++bt) {
      const size_t o = rowoff + b0 + bt * 16 + qq * 4;
      if constexpr (BF) {
        ushort4v p = {(unsigned short)sx, (unsigned short)(sx >> 16),
                      (unsigned short)sx, (unsigned short)sx};
        *(ushort4v*)(out + o) = p;
      } else {
        uint4 p = {sx, sx, sx, sx};
        *(uint4*)((unsigned*)out + o) = p;
      }
    }
  }
}

__global__ __launch_bounds__(256) void bl_probe(const void* __restrict__ inp,
                                                void* __restrict__ out) {
  if (detect_bf16(inp)) run_diag<unsigned short>((const unsigned short*)inp,
                                                 (unsigned short*)out);
  else                  run_diag<float>((const float*)inp, (float*)out);
}

// ---------------- main kernel: R6 structure, prefetch distance 3 ----------------
// One wg: one k-block (kb = wg&7, XCD-pinned) x 64 b-cols x all 256 m-rows.
// 4 waves, wave w owns m-rows m0=w*64..+63; A-fragments loaded as scalar
// k-gathers directly from global (dup absorbed by L2/L3); weights L2-resident.
// D: col(lane&15)=m, row(qq*4+reg)=b -> 4 consecutive b = wide store.
template <typename T, bool WBF>
__device__ __forceinline__ void run_bl(const T* __restrict__ inp,
                                       const T* __restrict__ blocks,
                                       const unsigned short* __restrict__ wbf,
                                       const T* __restrict__ bias,
                                       T* __restrict__ out) {
  constexpr bool BF = (sizeof(T) == 2);
  const int t    = threadIdx.x;
  const int wg   = blockIdx.x;
  const int kb   = wg & 7;          // XCD swizzle: one weight block per XCD L2
  const int b0   = (wg >> 3) << 6;  // 128 column tiles of 64
  const int lane = t & 63;
  const int cc   = lane & 15;
  const int qq   = lane >> 4;
  const int m0   = (t >> 6) << 6;   // wave's m offset (N dim)

  const unsigned short* wb_bf = WBF ? (wbf + kb * 65536) : nullptr;
  const T*              wb_t  = WBF ? nullptr : (blocks + kb * 65536);

  // per-lane A base: row (kb*256 + qq*8), col (b0 + cc)
  const T* abase = inp + (size_t)(kb * 256 + qq * 8) * BCOLS + b0 + cc;

  // Distance-3 buffers (parity s%3): A scalars + weight fragments.
  T      aB[3][4][8];   // [parity][bt][j]
  short8 wf[3][4];      // [parity][mt]

  auto loadA = [&](int s, int pb) {
    const T* p = abase + (size_t)s * 32 * BCOLS;
#pragma unroll
    for (int j = 0; j < 8; ++j) {
      const T* pj = p + (size_t)j * BCOLS;
#pragma unroll
      for (int bt = 0; bt < 4; ++bt) aB[pb][bt][j] = pj[bt * 16];
    }
  };
  auto loadW = [&](int s, int pb) {
    const int kgl = s * 32 + qq * 8;
#pragma unroll
    for (int mt = 0; mt < 4; ++mt) {
      const int row = m0 + mt * 16 + cc;
      if constexpr (WBF) {
        wf[pb][mt] = *(const short8*)(wb_bf + row * 256 + kgl);
      } else if constexpr (BF) {
        wf[pb][mt] = *(const short8*)((const unsigned short*)wb_t + row * 256 + kgl);
      } else {
        const float* ap = (const float*)wb_t + row * 256 + kgl;
        float4 w0 = *(const float4*)ap;
        float4 w1 = *(const float4*)(ap + 4);
        uint4 u;
        u.x = pk2(w0.x, w0.y); u.y = pk2(w0.z, w0.w);
        u.z = pk2(w1.x, w1.y); u.w = pk2(w1.z, w1.w);
        wf[pb][mt] = __builtin_bit_cast(short8, u);
      }
    }
  };

  f32x4 acc[4][4];
  const f32x4 z = {0.0f, 0.0f, 0.0f, 0.0f};
#pragma unroll
  for (int bt = 0; bt < 4; ++bt)
#pragma unroll
    for (int mt = 0; mt < 4; ++mt) acc[bt][mt] = z;

  // Prologue: steps 0,1,2 fully in flight (~24 KB/wave outstanding).
  loadA(0, 0); loadW(0, 0);
  loadA(1, 1); loadW(1, 1);
  loadA(2, 2); loadW(2, 2);

#pragma unroll
  for (int s = 0; s < 8; ++s) {
    const int pb = s % 3;            // s is compile-time (full unroll)
#pragma unroll
    for (int bt = 0; bt < 4; ++bt) {
      uint4 u;
      if constexpr (BF) {
        u.x = (unsigned)(unsigned short)aB[pb][bt][0] |
              ((unsigned)(unsigned short)aB[pb][bt][1] << 16);
        u.y = (unsigned)(unsigned short)aB[pb][bt][2] |
              ((unsigned)(unsigned short)aB[pb][bt][3] << 16);
        u.z = (unsigned)(unsigned short)aB[pb][bt][4] |
              ((unsigned)(unsigned short)aB[pb][bt][5] << 16);
        u.w = (unsigned)(unsigned short)aB[pb][bt][6] |
              ((unsigned)(unsigned short)aB[pb][bt][7] << 16);
      } else {
        u.x = pk2(aB[pb][bt][0], aB[pb][bt][1]);
        u.y = pk2(aB[pb][bt][2], aB[pb][bt][3]);
        u.z = pk2(aB[pb][bt][4], aB[pb][bt][5]);
        u.w = pk2(aB[pb][bt][6], aB[pb][bt][7]);
      }
      const short8 af = __builtin_bit_cast(short8, u);
#pragma unroll
      for (int mt = 0; mt < 4; ++mt)
        acc[bt][mt] = __builtin_amdgcn_mfma_f32_16x16x32_bf16(af, wf[pb][mt],
                                                              acc[bt][mt], 0, 0, 0);
    }
    // this parity's buffers now free: issue loads for step s+3
    if (s < 5) {
      loadA(s + 3, pb);
      loadW(s + 3, pb);
    }
  }

  // Epilogue: identical to R2/R6 (proven minimal-write store pattern).
  const int mrow0 = kb * 256 + m0;
  float bv[4];
#pragma unroll
  for (int mt = 0; mt < 4; ++mt) {
    if constexpr (BF) bv[mt] = bf2f((unsigned short)bias[mrow0 + mt * 16 + cc]);
    else              bv[mt] = bias[mrow0 + mt * 16 + cc];
  }
#pragma unroll
  for (int mt = 0; mt < 4; ++mt) {
    const size_t rowoff = (size_t)(mrow0 + mt * 16 + cc) * BCOLS;
#pragma unroll
    for (int bt = 0; bt < 4; ++bt) {
      f32x4 v = acc[bt][mt];
      const size_t o = rowoff + b0 + bt * 16 + qq * 4;
      if constexpr (BF) {
        ushort4v p = {f2bf(v[0] + bv[mt]), f2bf(v[1] + bv[mt]),
                      f2bf(v[2] + bv[mt]), f2bf(v[3] + bv[mt])};
        *(ushort4v*)(out + o) = p;
      } else {
        float4 p = {v[0] + bv[mt], v[1] + bv[mt], v[2] + bv[mt], v[3] + bv[mt]};
        *(float4*)(out + o) = p;
      }
    }
  }
}

template <bool WBF>
__global__ __launch_bounds__(256, 2) void BlockLinear_90752658965115_kernel(
    const void* __restrict__ inp, const void* __restrict__ blocks,
    const void* __restrict__ bias, const unsigned short* __restrict__ wbf,
    void* __restrict__ out) {
  if (detect_bf16(inp)) {
    run_bl<unsigned short, WBF>((const unsigned short*)inp,
                                (const unsigned short*)blocks, wbf,
                                (const unsigned short*)bias,
                                (unsigned short*)out);
  } else {
    run_bl<float, WBF>((const float*)inp, (const float*)blocks, wbf,
                       (const float*)bias, (float*)out);
  }
}

extern "C" void kernel_launch(void* const* d_in, const int* in_sizes, int n_in,
                              void* d_out, int out_size, void* d_ws, size_t ws_size,
                              hipStream_t stream) {
  (void)in_sizes; (void)n_in; (void)out_size;
  // Diagnostic probe: measures read+store pattern ceiling; output overwritten
  // by the main kernel below. Remove once its rocprof verdict is in.
  bl_probe<<<dim3(1024), dim3(256), 0, stream>>>(d_in[0], d_out);
  const size_t wbytes = (size_t)8 * 256 * 256 * 2;  // 1 MiB bf16 weights
  if (ws_size >= wbytes) {
    bl_convw<<<dim3(512), dim3(256), 0, stream>>>(d_in[1], (unsigned short*)d_ws);
    BlockLinear_90752658965115_kernel<true><<<dim3(1024), dim3(256), 0, stream>>>(
        d_in[0], d_in[1], d_in[2], (unsigned short*)d_ws, d_out);
  } else {
    BlockLinear_90752658965115_kernel<false><<<dim3(1024), dim3(256), 0, stream>>>(
        d_in[0], d_in[1], d_in[2], nullptr, d_out);
  }
}

// Round 6
// 148.505 us; speedup vs baseline: 1.1508x; 1.1508x over previous
//
#include <hip/hip_runtime.h>
#include <stdint.h>

// BlockLinear: out = block_diag(blocks) @ inp + bias
//   inp (2048,8192), blocks (8,256,256), bias (2048,)
// R8: R7 structure (direct-from-global, no LDS, no barriers, dist-3 buffers)
//     + sched_barrier(0) fences pinning the prefetch schedule. R6/R7 post-
//     mortem: VGPR_Count=76 both rounds proves the compiler SANK all prefetch
//     loads to their use points (a real dist-3 pipeline needs ~230 VGPR) ->
//     identical 58-63 us, 15-20% duty. R7's probe measured ~24 us (~5.3 TB/s)
//     for this exact read+store pattern with no compute -> pattern validated,
//     gap is purely the defeated pipeline. Fences: {MFMA s} SB(0) {loads s+3}
//     SB(0) per step; loads cannot sink across the fence. Probe removed.

#define BCOLS 8192

typedef __attribute__((ext_vector_type(8))) short short8;            // 8 bf16
typedef __attribute__((ext_vector_type(4))) float f32x4;             // MFMA acc
typedef __attribute__((ext_vector_type(4))) unsigned short ushort4v; // 8 B store

__device__ __forceinline__ unsigned short f2bf(float x) {
  unsigned u = __builtin_bit_cast(unsigned, x);
  u += 0x7FFFu + ((u >> 16) & 1u);  // RNE
  return (unsigned short)(u >> 16);
}
__device__ __forceinline__ float bf2f(unsigned short h) {
  unsigned u = ((unsigned)h) << 16;
  return __builtin_bit_cast(float, u);
}
__device__ __forceinline__ unsigned pk2(float a, float b) {
  return (unsigned)f2bf(a) | ((unsigned)f2bf(b) << 16);
}

// bf16 data: bits[8:15] of each dword = sign|exp byte clustered in [0x3B,0x43]
// for N(0,1); fp32: uniform mantissa bits. 32-sample vote, wave-uniform.
__device__ __forceinline__ bool detect_bf16(const void* p) {
  const unsigned* u = (const unsigned*)p;
  int votes = 0;
#pragma unroll
  for (int i = 0; i < 32; ++i) {
    unsigned b = (u[i] >> 8) & 0x7Fu;
    votes += (b >= 0x3Bu && b <= 0x43u) ? 1 : 0;
  }
  return votes >= 16;
}

// Pre-pass: blocks (any dtype) -> bf16 copy in d_ws. 524288 elems, 4/thread.
__global__ void bl_convw(const void* __restrict__ blocks,
                         unsigned short* __restrict__ wbf) {
  const int i = blockIdx.x * 256 + threadIdx.x;
  if (detect_bf16(blocks)) {
    ((ushort4v*)wbf)[i] = ((const ushort4v*)blocks)[i];
  } else {
    float4 v = ((const float4*)blocks)[i];
    ushort4v p = {f2bf(v.x), f2bf(v.y), f2bf(v.z), f2bf(v.w)};
    ((ushort4v*)wbf)[i] = p;
  }
}

// One wg: one k-block (kb = wg&7, XCD-pinned) x 64 b-cols x all 256 m-rows.
// 4 waves, wave w owns m-rows m0=w*64..+63; A-fragments loaded as scalar
// k-gathers directly from global (dup absorbed by L2/L3); weights L2-resident.
// D: col(lane&15)=m, row(qq*4+reg)=b -> 4 consecutive b = wide store.
template <typename T, bool WBF>
__device__ __forceinline__ void run_bl(const T* __restrict__ inp,
                                       const T* __restrict__ blocks,
                                       const unsigned short* __restrict__ wbf,
                                       const T* __restrict__ bias,
                                       T* __restrict__ out) {
  constexpr bool BF = (sizeof(T) == 2);
  const int t    = threadIdx.x;
  const int wg   = blockIdx.x;
  const int kb   = wg & 7;          // XCD swizzle: one weight block per XCD L2
  const int b0   = (wg >> 3) << 6;  // 128 column tiles of 64
  const int lane = t & 63;
  const int cc   = lane & 15;
  const int qq   = lane >> 4;
  const int m0   = (t >> 6) << 6;   // wave's m offset (N dim)

  const unsigned short* wb_bf = WBF ? (wbf + kb * 65536) : nullptr;
  const T*              wb_t  = WBF ? nullptr : (blocks + kb * 65536);

  // per-lane A base: row (kb*256 + qq*8), col (b0 + cc)
  const T* abase = inp + (size_t)(kb * 256 + qq * 8) * BCOLS + b0 + cc;

  // Distance-3 buffers (parity s%3): A scalars + weight fragments.
  T      aB[3][4][8];   // [parity][bt][j]
  short8 wf[3][4];      // [parity][mt]

  auto loadA = [&](int s, int pb) {
    const T* p = abase + (size_t)s * 32 * BCOLS;
#pragma unroll
    for (int j = 0; j < 8; ++j) {
      const T* pj = p + (size_t)j * BCOLS;
#pragma unroll
      for (int bt = 0; bt < 4; ++bt) aB[pb][bt][j] = pj[bt * 16];
    }
  };
  auto loadW = [&](int s, int pb) {
    const int kgl = s * 32 + qq * 8;
#pragma unroll
    for (int mt = 0; mt < 4; ++mt) {
      const int row = m0 + mt * 16 + cc;
      if constexpr (WBF) {
        wf[pb][mt] = *(const short8*)(wb_bf + row * 256 + kgl);
      } else if constexpr (BF) {
        wf[pb][mt] = *(const short8*)((const unsigned short*)wb_t + row * 256 + kgl);
      } else {
        const float* ap = (const float*)wb_t + row * 256 + kgl;
        float4 w0 = *(const float4*)ap;
        float4 w1 = *(const float4*)(ap + 4);
        uint4 u;
        u.x = pk2(w0.x, w0.y); u.y = pk2(w0.z, w0.w);
        u.z = pk2(w1.x, w1.y); u.w = pk2(w1.z, w1.w);
        wf[pb][mt] = __builtin_bit_cast(short8, u);
      }
    }
  };

  f32x4 acc[4][4];
  const f32x4 z = {0.0f, 0.0f, 0.0f, 0.0f};
#pragma unroll
  for (int bt = 0; bt < 4; ++bt)
#pragma unroll
    for (int mt = 0; mt < 4; ++mt) acc[bt][mt] = z;

  // Prologue: steps 0,1,2 fully in flight (~24 KB/wave outstanding).
  loadA(0, 0); loadW(0, 0);
  loadA(1, 1); loadW(1, 1);
  loadA(2, 2); loadW(2, 2);
  __builtin_amdgcn_sched_barrier(0);  // prologue loads stay above the loop

#pragma unroll
  for (int s = 0; s < 8; ++s) {
    const int pb = s % 3;            // s is compile-time (full unroll)
#pragma unroll
    for (int bt = 0; bt < 4; ++bt) {
      uint4 u;
      if constexpr (BF) {
        u.x = (unsigned)(unsigned short)aB[pb][bt][0] |
              ((unsigned)(unsigned short)aB[pb][bt][1] << 16);
        u.y = (unsigned)(unsigned short)aB[pb][bt][2] |
              ((unsigned)(unsigned short)aB[pb][bt][3] << 16);
        u.z = (unsigned)(unsigned short)aB[pb][bt][4] |
              ((unsigned)(unsigned short)aB[pb][bt][5] << 16);
        u.w = (unsigned)(unsigned short)aB[pb][bt][6] |
              ((unsigned)(unsigned short)aB[pb][bt][7] << 16);
      } else {
        u.x = pk2(aB[pb][bt][0], aB[pb][bt][1]);
        u.y = pk2(aB[pb][bt][2], aB[pb][bt][3]);
        u.z = pk2(aB[pb][bt][4], aB[pb][bt][5]);
        u.w = pk2(aB[pb][bt][6], aB[pb][bt][7]);
      }
      const short8 af = __builtin_bit_cast(short8, u);
#pragma unroll
      for (int mt = 0; mt < 4; ++mt)
        acc[bt][mt] = __builtin_amdgcn_mfma_f32_16x16x32_bf16(af, wf[pb][mt],
                                                              acc[bt][mt], 0, 0, 0);
    }
    // Fence 1: loads below cannot hoist above the MFMA cluster (WAR on aB[pb]
    // also forbids it); Fence 2 (critical): loads for s+3 CANNOT SINK into
    // later iterations — this is what the compiler did to R6/R7 (VGPR=76).
    __builtin_amdgcn_sched_barrier(0);
    if (s < 5) {
      loadA(s + 3, pb);
      loadW(s + 3, pb);
    }
    __builtin_amdgcn_sched_barrier(0);
  }

  // Epilogue: identical to R2/R6 (proven minimal-write store pattern).
  const int mrow0 = kb * 256 + m0;
  float bv[4];
#pragma unroll
  for (int mt = 0; mt < 4; ++mt) {
    if constexpr (BF) bv[mt] = bf2f((unsigned short)bias[mrow0 + mt * 16 + cc]);
    else              bv[mt] = bias[mrow0 + mt * 16 + cc];
  }
#pragma unroll
  for (int mt = 0; mt < 4; ++mt) {
    const size_t rowoff = (size_t)(mrow0 + mt * 16 + cc) * BCOLS;
#pragma unroll
    for (int bt = 0; bt < 4; ++bt) {
      f32x4 v = acc[bt][mt];
      const size_t o = rowoff + b0 + bt * 16 + qq * 4;
      if constexpr (BF) {
        ushort4v p = {f2bf(v[0] + bv[mt]), f2bf(v[1] + bv[mt]),
                      f2bf(v[2] + bv[mt]), f2bf(v[3] + bv[mt])};
        *(ushort4v*)(out + o) = p;
      } else {
        float4 p = {v[0] + bv[mt], v[1] + bv[mt], v[2] + bv[mt], v[3] + bv[mt]};
        *(float4*)(out + o) = p;
      }
    }
  }
}

template <bool WBF>
__global__ __launch_bounds__(256, 2) void BlockLinear_90752658965115_kernel(
    const void* __restrict__ inp, const void* __restrict__ blocks,
    const void* __restrict__ bias, const unsigned short* __restrict__ wbf,
    void* __restrict__ out) {
  if (detect_bf16(inp)) {
    run_bl<unsigned short, WBF>((const unsigned short*)inp,
                                (const unsigned short*)blocks, wbf,
                                (const unsigned short*)bias,
                                (unsigned short*)out);
  } else {
    run_bl<float, WBF>((const float*)inp, (const float*)blocks, wbf,
                       (const float*)bias, (float*)out);
  }
}

extern "C" void kernel_launch(void* const* d_in, const int* in_sizes, int n_in,
                              void* d_out, int out_size, void* d_ws, size_t ws_size,
                              hipStream_t stream) {
  (void)in_sizes; (void)n_in; (void)out_size;
  const size_t wbytes = (size_t)8 * 256 * 256 * 2;  // 1 MiB bf16 weights
  if (ws_size >= wbytes) {
    bl_convw<<<dim3(512), dim3(256), 0, stream>>>(d_in[1], (unsigned short*)d_ws);
    BlockLinear_90752658965115_kernel<true><<<dim3(1024), dim3(256), 0, stream>>>(
        d_in[0], d_in[1], d_in[2], (unsigned short*)d_ws, d_out);
  } else {
    BlockLinear_90752658965115_kernel<false><<<dim3(1024), dim3(256), 0, stream>>>(
        d_in[0], d_in[1], d_in[2], nullptr, d_out);
  }
}

// Round 8
// 138.178 us; speedup vs baseline: 1.2368x; 1.0747x over previous
//
#include <hip/hip_runtime.h>
#include <stdint.h>

// BlockLinear: out = block_diag(blocks) @ inp + bias
//   inp (2048,8192), blocks (8,256,256), bias (2048,)
// R10 (= R9 identical resubmit after 2nd infra failure; audit clean, R1's
//     identical-resubmit precedent): probe-style staging. R6/R7/R8: every
//     interleaved-prefetch variant lands 55-60us (in-flight ~4-5 loads/wave vs
//     ~700cy latency); R5's probe (all loads at once, same mapping+stores) ran
//     ~24us (~5.3 TB/s). So: issue the wg's ENTIRE A-tile upfront (32 loads,
//     256B/thread = 64KB/wg in flight), sched_barrier(0) pin (R8 proved the
//     mechanism: VGPR 76->128), 8x ds_write_b128 into quad LDS [4][64][72]
//     (36KB), ONE __syncthreads, then 4 chunks of pure LDS->MFMA with R2's
//     weight double-buffer, R2's proven epilogue. No mid-kernel barriers.

#define BCOLS 8192

typedef __attribute__((ext_vector_type(8))) short short8;            // 8 bf16
typedef __attribute__((ext_vector_type(4))) float f32x4;             // MFMA acc
typedef __attribute__((ext_vector_type(4))) unsigned short ushort4v; // 8 B store

__device__ __forceinline__ unsigned short f2bf(float x) {
  unsigned u = __builtin_bit_cast(unsigned, x);
  u += 0x7FFFu + ((u >> 16) & 1u);  // RNE
  return (unsigned short)(u >> 16);
}
__device__ __forceinline__ float bf2f(unsigned short h) {
  unsigned u = ((unsigned)h) << 16;
  return __builtin_bit_cast(float, u);
}
__device__ __forceinline__ unsigned pk2(float a, float b) {
  return (unsigned)f2bf(a) | ((unsigned)f2bf(b) << 16);
}

// bf16 data: bits[8:15] of each dword = sign|exp byte clustered in [0x3B,0x43]
// for N(0,1); fp32: uniform mantissa bits. 32-sample vote, wave-uniform.
__device__ __forceinline__ bool detect_bf16(const void* p) {
  const unsigned* u = (const unsigned*)p;
  int votes = 0;
#pragma unroll
  for (int i = 0; i < 32; ++i) {
    unsigned b = (u[i] >> 8) & 0x7Fu;
    votes += (b >= 0x3Bu && b <= 0x43u) ? 1 : 0;
  }
  return votes >= 16;
}

// Pre-pass: blocks (any dtype) -> bf16 copy in d_ws. 524288 elems, 4/thread.
__global__ void bl_convw(const void* __restrict__ blocks,
                         unsigned short* __restrict__ wbf) {
  const int i = blockIdx.x * 256 + threadIdx.x;
  if (detect_bf16(blocks)) {
    ((ushort4v*)wbf)[i] = ((const ushort4v*)blocks)[i];
  } else {
    float4 v = ((const float4*)blocks)[i];
    ushort4v p = {f2bf(v.x), f2bf(v.y), f2bf(v.z), f2bf(v.w)};
    ((ushort4v*)wbf)[i] = p;
  }
}

// One wg: one k-block (kb = wg&7, XCD-pinned) x 64 b-cols x all 256 m-rows.
// 4 waves: wave w owns m-range w*64..+63 (MFMA N dim); b = MFMA M dim.
// A-operand = inp^T fragment from LDS (b-major, k-contiguous).
// B-operand = weight rows from global/ws (k-contiguous), double-buffered regs.
// D: col(lane&15) = m, row(quad*4+reg) = b -> reg = 4 consecutive b = wide store.
template <typename T, bool WBF>
__device__ __forceinline__ void run_bl(const T* __restrict__ inp,
                                       const T* __restrict__ blocks,
                                       const unsigned short* __restrict__ wbf,
                                       const T* __restrict__ bias,
                                       T* __restrict__ out,
                                       unsigned short (&Blds)[4][64][72]) {
  constexpr bool BF = (sizeof(T) == 2);
  const int t    = threadIdx.x;
  const int wg   = blockIdx.x;
  const int kb   = wg & 7;          // XCD swizzle: one weight block per XCD L2
  const int b0   = (wg >> 3) << 6;  // 128 column tiles of 64
  const int lane = t & 63;
  const int cc   = lane & 15;
  const int qq   = lane >> 4;
  const int m0   = (t >> 6) << 6;   // wave's m offset (N dim)

  // staging: thread owns col-pair (2cp,2cp+1) x rows rg*8..rg*8+7 per 64-k chunk
  const int cp = t & 31;
  const int rg = t >> 5;
  const size_t inbase = (size_t)(kb * 256 + rg * 8) * BCOLS + b0 + cp * 2;

  const unsigned short* wb_bf = WBF ? (wbf + kb * 65536) : nullptr;
  const T*              wb_t  = WBF ? nullptr : (blocks + kb * 65536);

  // ALL FOUR chunks' stage registers live at once (probe-style full issue).
  unsigned Vu[4][8];
  float2   Vf[4][8];

  auto loadStage = [&](int ch) {
    const size_t o = inbase + (size_t)(ch * 64) * BCOLS;
#pragma unroll
    for (int rr = 0; rr < 8; ++rr) {
      if constexpr (BF) Vu[ch][rr] = *(const unsigned*)(inp + o + (size_t)rr * BCOLS);
      else              Vf[ch][rr] = *(const float2*)(inp + o + (size_t)rr * BCOLS);
    }
  };
  auto writeStage = [&](int ch) {
    uint4 e, o4;
    if constexpr (BF) {
      e.x  = (Vu[ch][0] & 0xFFFFu) | (Vu[ch][1] << 16);
      e.y  = (Vu[ch][2] & 0xFFFFu) | (Vu[ch][3] << 16);
      e.z  = (Vu[ch][4] & 0xFFFFu) | (Vu[ch][5] << 16);
      e.w  = (Vu[ch][6] & 0xFFFFu) | (Vu[ch][7] << 16);
      o4.x = (Vu[ch][0] >> 16) | (Vu[ch][1] & 0xFFFF0000u);
      o4.y = (Vu[ch][2] >> 16) | (Vu[ch][3] & 0xFFFF0000u);
      o4.z = (Vu[ch][4] >> 16) | (Vu[ch][5] & 0xFFFF0000u);
      o4.w = (Vu[ch][6] >> 16) | (Vu[ch][7] & 0xFFFF0000u);
    } else {
      e.x  = pk2(Vf[ch][0].x, Vf[ch][1].x);
      e.y  = pk2(Vf[ch][2].x, Vf[ch][3].x);
      e.z  = pk2(Vf[ch][4].x, Vf[ch][5].x);
      e.w  = pk2(Vf[ch][6].x, Vf[ch][7].x);
      o4.x = pk2(Vf[ch][0].y, Vf[ch][1].y);
      o4.y = pk2(Vf[ch][2].y, Vf[ch][3].y);
      o4.z = pk2(Vf[ch][4].y, Vf[ch][5].y);
      o4.w = pk2(Vf[ch][6].y, Vf[ch][7].y);
    }
    *(uint4*)&Blds[ch][cp * 2][rg * 8]     = e;
    *(uint4*)&Blds[ch][cp * 2 + 1][rg * 8] = o4;
  };
  auto loadW = [&](int ch, int kk, short8 (&wf)[4]) {
    const int kgl = ch * 64 + kk * 32 + qq * 8;
#pragma unroll
    for (int mt = 0; mt < 4; ++mt) {
      const int row = m0 + mt * 16 + cc;
      if constexpr (WBF) {
        wf[mt] = *(const short8*)(wb_bf + row * 256 + kgl);
      } else if constexpr (BF) {
        wf[mt] = *(const short8*)((const unsigned short*)wb_t + row * 256 + kgl);
      } else {
        const float* ap = (const float*)wb_t + row * 256 + kgl;
        float4 w0 = *(const float4*)ap;
        float4 w1 = *(const float4*)(ap + 4);
        uint4 u;
        u.x = pk2(w0.x, w0.y); u.y = pk2(w0.z, w0.w);
        u.z = pk2(w1.x, w1.y); u.w = pk2(w1.z, w1.w);
        wf[mt] = __builtin_bit_cast(short8, u);
      }
    }
  };

  // ---- Phase 1: issue the ENTIRE A-tile (32 loads, 256 B/thread in flight) ----
  loadStage(0);
  loadStage(1);
  loadStage(2);
  loadStage(3);
  __builtin_amdgcn_sched_barrier(0);  // pin: no sinking into later phases

  short8 wfc[4], wfn[4];
  loadW(0, 0, wfc);
#pragma unroll
  for (int mt = 0; mt < 4; ++mt) wfn[mt] = wfc[mt];

  // ---- Phase 2: drain into LDS (counted vmcnt per chunk), ONE barrier ----
  writeStage(0);
  writeStage(1);
  writeStage(2);
  writeStage(3);
  __syncthreads();   // only barrier in the kernel; loads already completed

  f32x4 acc[4][4];
  const f32x4 z = {0.0f, 0.0f, 0.0f, 0.0f};
#pragma unroll
  for (int bt = 0; bt < 4; ++bt)
#pragma unroll
    for (int mt = 0; mt < 4; ++mt) acc[bt][mt] = z;

  // ---- Phase 3: pure LDS->MFMA, weight double-buffer (R2 schedule) ----
#pragma unroll
  for (int ch = 0; ch < 4; ++ch) {
#pragma unroll
    for (int kk = 0; kk < 2; ++kk) {
      if (kk == 0)      loadW(ch, 1, wfn);        // weight prefetch, next kk
      else if (ch < 3)  loadW(ch + 1, 0, wfn);    // weight prefetch, next chunk
      const int koff = kk * 32 + qq * 8;
#pragma unroll
      for (int bt = 0; bt < 4; ++bt) {
        short8 af = *(const short8*)&Blds[ch][bt * 16 + cc][koff];
#pragma unroll
        for (int mt = 0; mt < 4; ++mt)
          acc[bt][mt] = __builtin_amdgcn_mfma_f32_16x16x32_bf16(af, wfc[mt],
                                                                acc[bt][mt], 0, 0, 0);
      }
#pragma unroll
      for (int mt = 0; mt < 4; ++mt) wfc[mt] = wfn[mt];
    }
  }

  // ---- Epilogue: identical to R2 (proven 65.5 MB store pattern) ----
  const int mrow0 = kb * 256 + m0;
  float bv[4];
#pragma unroll
  for (int mt = 0; mt < 4; ++mt) {
    if constexpr (BF) bv[mt] = bf2f((unsigned short)bias[mrow0 + mt * 16 + cc]);
    else              bv[mt] = bias[mrow0 + mt * 16 + cc];
  }
#pragma unroll
  for (int mt = 0; mt < 4; ++mt) {
    const size_t rowoff = (size_t)(mrow0 + mt * 16 + cc) * BCOLS;
#pragma unroll
    for (int bt = 0; bt < 4; ++bt) {
      f32x4 v = acc[bt][mt];
      const size_t o = rowoff + b0 + bt * 16 + qq * 4;
      if constexpr (BF) {
        ushort4v p = {f2bf(v[0] + bv[mt]), f2bf(v[1] + bv[mt]),
                      f2bf(v[2] + bv[mt]), f2bf(v[3] + bv[mt])};
        *(ushort4v*)(out + o) = p;
      } else {
        float4 p = {v[0] + bv[mt], v[1] + bv[mt], v[2] + bv[mt], v[3] + bv[mt]};
        *(float4*)(out + o) = p;
      }
    }
  }
}

template <bool WBF>
__global__ __launch_bounds__(256, 2) void BlockLinear_90752658965115_kernel(
    const void* __restrict__ inp, const void* __restrict__ blocks,
    const void* __restrict__ bias, const unsigned short* __restrict__ wbf,
    void* __restrict__ out) {
  __shared__ __align__(16) unsigned short Blds[4][64][72];  // 36 KiB
  if (detect_bf16(inp)) {
    run_bl<unsigned short, WBF>((const unsigned short*)inp,
                                (const unsigned short*)blocks, wbf,
                                (const unsigned short*)bias,
                                (unsigned short*)out, Blds);
  } else {
    run_bl<float, WBF>((const float*)inp, (const float*)blocks, wbf,
                       (const float*)bias, (float*)out, Blds);
  }
}

extern "C" void kernel_launch(void* const* d_in, const int* in_sizes, int n_in,
                              void* d_out, int out_size, void* d_ws, size_t ws_size,
                              hipStream_t stream) {
  (void)in_sizes; (void)n_in; (void)out_size;
  const size_t wbytes = (size_t)8 * 256 * 256 * 2;  // 1 MiB bf16 weights
  if (ws_size >= wbytes) {
    bl_convw<<<dim3(512), dim3(256), 0, stream>>>(d_in[1], (unsigned short*)d_ws);
    BlockLinear_90752658965115_kernel<true><<<dim3(1024), dim3(256), 0, stream>>>(
        d_in[0], d_in[1], d_in[2], (unsigned short*)d_ws, d_out);
  } else {
    BlockLinear_90752658965115_kernel<false><<<dim3(1024), dim3(256), 0, stream>>>(
        d_in[0], d_in[1], d_in[2], nullptr, d_out);
  }
}

// Round 9
// 135.025 us; speedup vs baseline: 1.2657x; 1.0234x over previous
//
#include <hip/hip_runtime.h>
#include <stdint.h>

// BlockLinear: out = block_diag(blocks) @ inp + bias
//   inp (2048,8192), blocks (8,256,256), bias (2048,)
// R11: R10 + LDS padded [4][64][72] -> [7][64][72] (63 KB, planes 4-6 unused)
//     to force 2 wgs/CU residency -> the 1024-wg grid runs as TWO generations.
//     R10 post-mortem: per-wg pipeline is clean (VGPR 68, full upfront issue,
//     ideal traffic 33.4/65.5 MB), but ONE generation (4/CU resident = grid)
//     serializes the global read phase (~13us) and write drain (~24us) ->
//     49-53us = R+C+W. Gen-2 loads (L3-heavy) now overlap gen-1 store drain
//     (HBM writes). Store granule stays 128B/row (R4 lesson: WRITE 2x if split).

#define BCOLS 8192

typedef __attribute__((ext_vector_type(8))) short short8;            // 8 bf16
typedef __attribute__((ext_vector_type(4))) float f32x4;             // MFMA acc
typedef __attribute__((ext_vector_type(4))) unsigned short ushort4v; // 8 B store

__device__ __forceinline__ unsigned short f2bf(float x) {
  unsigned u = __builtin_bit_cast(unsigned, x);
  u += 0x7FFFu + ((u >> 16) & 1u);  // RNE
  return (unsigned short)(u >> 16);
}
__device__ __forceinline__ float bf2f(unsigned short h) {
  unsigned u = ((unsigned)h) << 16;
  return __builtin_bit_cast(float, u);
}
__device__ __forceinline__ unsigned pk2(float a, float b) {
  return (unsigned)f2bf(a) | ((unsigned)f2bf(b) << 16);
}

// bf16 data: bits[8:15] of each dword = sign|exp byte clustered in [0x3B,0x43]
// for N(0,1); fp32: uniform mantissa bits. 32-sample vote, wave-uniform.
__device__ __forceinline__ bool detect_bf16(const void* p) {
  const unsigned* u = (const unsigned*)p;
  int votes = 0;
#pragma unroll
  for (int i = 0; i < 32; ++i) {
    unsigned b = (u[i] >> 8) & 0x7Fu;
    votes += (b >= 0x3Bu && b <= 0x43u) ? 1 : 0;
  }
  return votes >= 16;
}

// Pre-pass: blocks (any dtype) -> bf16 copy in d_ws. 524288 elems, 4/thread.
__global__ void bl_convw(const void* __restrict__ blocks,
                         unsigned short* __restrict__ wbf) {
  const int i = blockIdx.x * 256 + threadIdx.x;
  if (detect_bf16(blocks)) {
    ((ushort4v*)wbf)[i] = ((const ushort4v*)blocks)[i];
  } else {
    float4 v = ((const float4*)blocks)[i];
    ushort4v p = {f2bf(v.x), f2bf(v.y), f2bf(v.z), f2bf(v.w)};
    ((ushort4v*)wbf)[i] = p;
  }
}

// One wg: one k-block (kb = wg&7, XCD-pinned) x 64 b-cols x all 256 m-rows.
// 4 waves: wave w owns m-range w*64..+63 (MFMA N dim); b = MFMA M dim.
// A-operand = inp^T fragment from LDS (b-major, k-contiguous).
// B-operand = weight rows from global/ws (k-contiguous), double-buffered regs.
// D: col(lane&15) = m, row(quad*4+reg) = b -> reg = 4 consecutive b = wide store.
template <typename T, bool WBF>
__device__ __forceinline__ void run_bl(const T* __restrict__ inp,
                                       const T* __restrict__ blocks,
                                       const unsigned short* __restrict__ wbf,
                                       const T* __restrict__ bias,
                                       T* __restrict__ out,
                                       unsigned short (&Blds)[7][64][72]) {
  constexpr bool BF = (sizeof(T) == 2);
  const int t    = threadIdx.x;
  const int wg   = blockIdx.x;
  const int kb   = wg & 7;          // XCD swizzle: one weight block per XCD L2
  const int b0   = (wg >> 3) << 6;  // 128 column tiles of 64
  const int lane = t & 63;
  const int cc   = lane & 15;
  const int qq   = lane >> 4;
  const int m0   = (t >> 6) << 6;   // wave's m offset (N dim)

  // staging: thread owns col-pair (2cp,2cp+1) x rows rg*8..rg*8+7 per 64-k chunk
  const int cp = t & 31;
  const int rg = t >> 5;
  const size_t inbase = (size_t)(kb * 256 + rg * 8) * BCOLS + b0 + cp * 2;

  const unsigned short* wb_bf = WBF ? (wbf + kb * 65536) : nullptr;
  const T*              wb_t  = WBF ? nullptr : (blocks + kb * 65536);

  // ALL FOUR chunks' stage registers live at once (probe-style full issue).
  unsigned Vu[4][8];
  float2   Vf[4][8];

  auto loadStage = [&](int ch) {
    const size_t o = inbase + (size_t)(ch * 64) * BCOLS;
#pragma unroll
    for (int rr = 0; rr < 8; ++rr) {
      if constexpr (BF) Vu[ch][rr] = *(const unsigned*)(inp + o + (size_t)rr * BCOLS);
      else              Vf[ch][rr] = *(const float2*)(inp + o + (size_t)rr * BCOLS);
    }
  };
  auto writeStage = [&](int ch) {
    uint4 e, o4;
    if constexpr (BF) {
      e.x  = (Vu[ch][0] & 0xFFFFu) | (Vu[ch][1] << 16);
      e.y  = (Vu[ch][2] & 0xFFFFu) | (Vu[ch][3] << 16);
      e.z  = (Vu[ch][4] & 0xFFFFu) | (Vu[ch][5] << 16);
      e.w  = (Vu[ch][6] & 0xFFFFu) | (Vu[ch][7] << 16);
      o4.x = (Vu[ch][0] >> 16) | (Vu[ch][1] & 0xFFFF0000u);
      o4.y = (Vu[ch][2] >> 16) | (Vu[ch][3] & 0xFFFF0000u);
      o4.z = (Vu[ch][4] >> 16) | (Vu[ch][5] & 0xFFFF0000u);
      o4.w = (Vu[ch][6] >> 16) | (Vu[ch][7] & 0xFFFF0000u);
    } else {
      e.x  = pk2(Vf[ch][0].x, Vf[ch][1].x);
      e.y  = pk2(Vf[ch][2].x, Vf[ch][3].x);
      e.z  = pk2(Vf[ch][4].x, Vf[ch][5].x);
      e.w  = pk2(Vf[ch][6].x, Vf[ch][7].x);
      o4.x = pk2(Vf[ch][0].y, Vf[ch][1].y);
      o4.y = pk2(Vf[ch][2].y, Vf[ch][3].y);
      o4.z = pk2(Vf[ch][4].y, Vf[ch][5].y);
      o4.w = pk2(Vf[ch][6].y, Vf[ch][7].y);
    }
    *(uint4*)&Blds[ch][cp * 2][rg * 8]     = e;
    *(uint4*)&Blds[ch][cp * 2 + 1][rg * 8] = o4;
  };
  auto loadW = [&](int ch, int kk, short8 (&wf)[4]) {
    const int kgl = ch * 64 + kk * 32 + qq * 8;
#pragma unroll
    for (int mt = 0; mt < 4; ++mt) {
      const int row = m0 + mt * 16 + cc;
      if constexpr (WBF) {
        wf[mt] = *(const short8*)(wb_bf + row * 256 + kgl);
      } else if constexpr (BF) {
        wf[mt] = *(const short8*)((const unsigned short*)wb_t + row * 256 + kgl);
      } else {
        const float* ap = (const float*)wb_t + row * 256 + kgl;
        float4 w0 = *(const float4*)ap;
        float4 w1 = *(const float4*)(ap + 4);
        uint4 u;
        u.x = pk2(w0.x, w0.y); u.y = pk2(w0.z, w0.w);
        u.z = pk2(w1.x, w1.y); u.w = pk2(w1.z, w1.w);
        wf[mt] = __builtin_bit_cast(short8, u);
      }
    }
  };

  // ---- Phase 1: issue the ENTIRE A-tile (32 loads, 256 B/thread in flight) ----
  loadStage(0);
  loadStage(1);
  loadStage(2);
  loadStage(3);
  __builtin_amdgcn_sched_barrier(0);  // pin: no sinking into later phases

  short8 wfc[4], wfn[4];
  loadW(0, 0, wfc);
#pragma unroll
  for (int mt = 0; mt < 4; ++mt) wfn[mt] = wfc[mt];

  // ---- Phase 2: drain into LDS (counted vmcnt per chunk), ONE barrier ----
  writeStage(0);
  writeStage(1);
  writeStage(2);
  writeStage(3);
  __syncthreads();   // only barrier in the kernel; loads already completed

  f32x4 acc[4][4];
  const f32x4 z = {0.0f, 0.0f, 0.0f, 0.0f};
#pragma unroll
  for (int bt = 0; bt < 4; ++bt)
#pragma unroll
    for (int mt = 0; mt < 4; ++mt) acc[bt][mt] = z;

  // ---- Phase 3: pure LDS->MFMA, weight double-buffer (R2 schedule) ----
#pragma unroll
  for (int ch = 0; ch < 4; ++ch) {
#pragma unroll
    for (int kk = 0; kk < 2; ++kk) {
      if (kk == 0)      loadW(ch, 1, wfn);        // weight prefetch, next kk
      else if (ch < 3)  loadW(ch + 1, 0, wfn);    // weight prefetch, next chunk
      const int koff = kk * 32 + qq * 8;
#pragma unroll
      for (int bt = 0; bt < 4; ++bt) {
        short8 af = *(const short8*)&Blds[ch][bt * 16 + cc][koff];
#pragma unroll
        for (int mt = 0; mt < 4; ++mt)
          acc[bt][mt] = __builtin_amdgcn_mfma_f32_16x16x32_bf16(af, wfc[mt],
                                                                acc[bt][mt], 0, 0, 0);
      }
#pragma unroll
      for (int mt = 0; mt < 4; ++mt) wfc[mt] = wfn[mt];
    }
  }

  // ---- Epilogue: identical to R2 (proven 65.5 MB store pattern) ----
  const int mrow0 = kb * 256 + m0;
  float bv[4];
#pragma unroll
  for (int mt = 0; mt < 4; ++mt) {
    if constexpr (BF) bv[mt] = bf2f((unsigned short)bias[mrow0 + mt * 16 + cc]);
    else              bv[mt] = bias[mrow0 + mt * 16 + cc];
  }
#pragma unroll
  for (int mt = 0; mt < 4; ++mt) {
    const size_t rowoff = (size_t)(mrow0 + mt * 16 + cc) * BCOLS;
#pragma unroll
    for (int bt = 0; bt < 4; ++bt) {
      f32x4 v = acc[bt][mt];
      const size_t o = rowoff + b0 + bt * 16 + qq * 4;
      if constexpr (BF) {
        ushort4v p = {f2bf(v[0] + bv[mt]), f2bf(v[1] + bv[mt]),
                      f2bf(v[2] + bv[mt]), f2bf(v[3] + bv[mt])};
        *(ushort4v*)(out + o) = p;
      } else {
        float4 p = {v[0] + bv[mt], v[1] + bv[mt], v[2] + bv[mt], v[3] + bv[mt]};
        *(float4*)(out + o) = p;
      }
    }
  }
}

template <bool WBF>
__global__ __launch_bounds__(256, 2) void BlockLinear_90752658965115_kernel(
    const void* __restrict__ inp, const void* __restrict__ blocks,
    const void* __restrict__ bias, const unsigned short* __restrict__ wbf,
    void* __restrict__ out) {
  // 63 KB: planes 0-3 used, 4-6 are residency ballast (2 wgs/CU -> the
  // 1024-wg grid runs as 2 generations; gen-2 reads overlap gen-1 writes).
  __shared__ __align__(16) unsigned short Blds[7][64][72];
  if (detect_bf16(inp)) {
    run_bl<unsigned short, WBF>((const unsigned short*)inp,
                                (const unsigned short*)blocks, wbf,
                                (const unsigned short*)bias,
                                (unsigned short*)out, Blds);
  } else {
    run_bl<float, WBF>((const float*)inp, (const float*)blocks, wbf,
                       (const float*)bias, (float*)out, Blds);
  }
}

extern "C" void kernel_launch(void* const* d_in, const int* in_sizes, int n_in,
                              void* d_out, int out_size, void* d_ws, size_t ws_size,
                              hipStream_t stream) {
  (void)in_sizes; (void)n_in; (void)out_size;
  const size_t wbytes = (size_t)8 * 256 * 256 * 2;  // 1 MiB bf16 weights
  if (ws_size >= wbytes) {
    bl_convw<<<dim3(512), dim3(256), 0, stream>>>(d_in[1], (unsigned short*)d_ws);
    BlockLinear_90752658965115_kernel<true><<<dim3(1024), dim3(256), 0, stream>>>(
        d_in[0], d_in[1], d_in[2], (unsigned short*)d_ws, d_out);
  } else {
    BlockLinear_90752658965115_kernel<false><<<dim3(1024), dim3(256), 0, stream>>>(
        d_in[0], d_in[1], d_in[2], nullptr, d_out);
  }
}

// Round 10
// 130.083 us; speedup vs baseline: 1.3137x; 1.0380x over previous
//
#include <hip/hip_runtime.h>
#include <stdint.h>

// BlockLinear: out = block_diag(blocks) @ inp + bias
//   inp (2048,8192), blocks (8,256,256), bias (2048,)
// R12: intra-wg 2-tile read/write pipeline. R11 (2 coarse generations) = 43us,
//     confirmed phase-overlap mechanism but edges still serialized. Now grid
//     512, each wg = 128-col supertile as TWO sequential 64-col tiles (store
//     granule preserved; R4 lesson). Loads B issued BEFORE stores A; writeLDS B
//     waits loads via counted vmcnt(16) while A-stores stay in flight; raw
//     lgkmcnt barriers (R4/R5-validated) avoid the __syncthreads vmcnt drain.
//     Every store burst except the last drains under the next tile's loads.
//     2 wgs/CU (36 KB LDS), launch_bounds(256,2).

#define BCOLS 8192

typedef __attribute__((ext_vector_type(8))) short short8;            // 8 bf16
typedef __attribute__((ext_vector_type(4))) float f32x4;             // MFMA acc
typedef __attribute__((ext_vector_type(4))) unsigned short ushort4v; // 8 B store

__device__ __forceinline__ unsigned short f2bf(float x) {
  unsigned u = __builtin_bit_cast(unsigned, x);
  u += 0x7FFFu + ((u >> 16) & 1u);  // RNE
  return (unsigned short)(u >> 16);
}
__device__ __forceinline__ float bf2f(unsigned short h) {
  unsigned u = ((unsigned)h) << 16;
  return __builtin_bit_cast(float, u);
}
__device__ __forceinline__ unsigned pk2(float a, float b) {
  return (unsigned)f2bf(a) | ((unsigned)f2bf(b) << 16);
}

// bf16 data: bits[8:15] of each dword = sign|exp byte clustered in [0x3B,0x43]
// for N(0,1); fp32: uniform mantissa bits. 32-sample vote, wave-uniform.
__device__ __forceinline__ bool detect_bf16(const void* p) {
  const unsigned* u = (const unsigned*)p;
  int votes = 0;
#pragma unroll
  for (int i = 0; i < 32; ++i) {
    unsigned b = (u[i] >> 8) & 0x7Fu;
    votes += (b >= 0x3Bu && b <= 0x43u) ? 1 : 0;
  }
  return votes >= 16;
}

// Pre-pass: blocks (any dtype) -> bf16 copy in d_ws. 524288 elems, 4/thread.
__global__ void bl_convw(const void* __restrict__ blocks,
                         unsigned short* __restrict__ wbf) {
  const int i = blockIdx.x * 256 + threadIdx.x;
  if (detect_bf16(blocks)) {
    ((ushort4v*)wbf)[i] = ((const ushort4v*)blocks)[i];
  } else {
    float4 v = ((const float4*)blocks)[i];
    ushort4v p = {f2bf(v.x), f2bf(v.y), f2bf(v.z), f2bf(v.w)};
    ((ushort4v*)wbf)[i] = p;
  }
}

// Raw barrier without the vmcnt(0) drain __syncthreads would emit: LDS
// ordering needs only lgkmcnt(0) (ds ops are lgkm-tracked). Global loads AND
// stores stay in flight across it. Correctness validated on HW (R4/R5 runs).
__device__ __forceinline__ void bar_nodrain() {
  asm volatile("s_waitcnt lgkmcnt(0)" ::: "memory");
  __builtin_amdgcn_s_barrier();
  asm volatile("" ::: "memory");
  __builtin_amdgcn_sched_barrier(0);
}

// One wg: one k-block (kb = wg&7, XCD-pinned) x 128 b-cols (two sequential
// 64-col tiles) x all 256 m-rows. 4 waves: wave w owns m-range w*64..+63.
// A-operand = inp^T fragment from LDS (b-major, k-contiguous).
// B-operand = weight rows from global/ws (k-contiguous), double-buffered regs.
// D: col(lane&15)=m, row(qq*4+reg)=b -> 4 consecutive b = wide store.
template <typename T, bool WBF>
__device__ __forceinline__ void run_bl(const T* __restrict__ inp,
                                       const T* __restrict__ blocks,
                                       const unsigned short* __restrict__ wbf,
                                       const T* __restrict__ bias,
                                       T* __restrict__ out,
                                       unsigned short (&Blds)[4][64][72]) {
  constexpr bool BF = (sizeof(T) == 2);
  const int t    = threadIdx.x;
  const int wg   = blockIdx.x;
  const int kb   = wg & 7;          // XCD swizzle: one weight block per XCD L2
  const int b0   = (wg >> 3) << 7;  // 64 supertiles of 128 cols
  const int lane = t & 63;
  const int cc   = lane & 15;
  const int qq   = lane >> 4;
  const int m0   = (t >> 6) << 6;   // wave's m offset (N dim)

  // staging: thread owns col-pair (2cp,2cp+1) x rows rg*8..+7 per 64-k chunk
  const int cp = t & 31;
  const int rg = t >> 5;
  const size_t inoff = (size_t)(kb * 256 + rg * 8) * BCOLS + cp * 2;

  const unsigned short* wb_bf = WBF ? (wbf + kb * 65536) : nullptr;
  const T*              wb_t  = WBF ? nullptr : (blocks + kb * 65536);

  // One stage register set, reused across tiles (WAR via writeStage).
  unsigned Vu[4][8];
  float2   Vf[4][8];

  auto loadStageAll = [&](int tb) {
#pragma unroll
    for (int ch = 0; ch < 4; ++ch) {
      const size_t o = inoff + (size_t)(ch * 64) * BCOLS + tb;
#pragma unroll
      for (int rr = 0; rr < 8; ++rr) {
        if constexpr (BF) Vu[ch][rr] = *(const unsigned*)(inp + o + (size_t)rr * BCOLS);
        else              Vf[ch][rr] = *(const float2*)(inp + o + (size_t)rr * BCOLS);
      }
    }
  };
  auto writeStageAll = [&]() {
#pragma unroll
    for (int ch = 0; ch < 4; ++ch) {
      uint4 e, o4;
      if constexpr (BF) {
        e.x  = (Vu[ch][0] & 0xFFFFu) | (Vu[ch][1] << 16);
        e.y  = (Vu[ch][2] & 0xFFFFu) | (Vu[ch][3] << 16);
        e.z  = (Vu[ch][4] & 0xFFFFu) | (Vu[ch][5] << 16);
        e.w  = (Vu[ch][6] & 0xFFFFu) | (Vu[ch][7] << 16);
        o4.x = (Vu[ch][0] >> 16) | (Vu[ch][1] & 0xFFFF0000u);
        o4.y = (Vu[ch][2] >> 16) | (Vu[ch][3] & 0xFFFF0000u);
        o4.z = (Vu[ch][4] >> 16) | (Vu[ch][5] & 0xFFFF0000u);
        o4.w = (Vu[ch][6] >> 16) | (Vu[ch][7] & 0xFFFF0000u);
      } else {
        e.x  = pk2(Vf[ch][0].x, Vf[ch][1].x);
        e.y  = pk2(Vf[ch][2].x, Vf[ch][3].x);
        e.z  = pk2(Vf[ch][4].x, Vf[ch][5].x);
        e.w  = pk2(Vf[ch][6].x, Vf[ch][7].x);
        o4.x = pk2(Vf[ch][0].y, Vf[ch][1].y);
        o4.y = pk2(Vf[ch][2].y, Vf[ch][3].y);
        o4.z = pk2(Vf[ch][4].y, Vf[ch][5].y);
        o4.w = pk2(Vf[ch][6].y, Vf[ch][7].y);
      }
      *(uint4*)&Blds[ch][cp * 2][rg * 8]     = e;
      *(uint4*)&Blds[ch][cp * 2 + 1][rg * 8] = o4;
    }
  };
  auto loadW = [&](int ch, int kk, short8 (&wf)[4]) {
    const int kgl = ch * 64 + kk * 32 + qq * 8;
#pragma unroll
    for (int mt = 0; mt < 4; ++mt) {
      const int row = m0 + mt * 16 + cc;
      if constexpr (WBF) {
        wf[mt] = *(const short8*)(wb_bf + row * 256 + kgl);
      } else if constexpr (BF) {
        wf[mt] = *(const short8*)((const unsigned short*)wb_t + row * 256 + kgl);
      } else {
        const float* ap = (const float*)wb_t + row * 256 + kgl;
        float4 w0 = *(const float4*)ap;
        float4 w1 = *(const float4*)(ap + 4);
        uint4 u;
        u.x = pk2(w0.x, w0.y); u.y = pk2(w0.z, w0.w);
        u.z = pk2(w1.x, w1.y); u.w = pk2(w1.z, w1.w);
        wf[mt] = __builtin_bit_cast(short8, u);
      }
    }
  };

  f32x4 acc[4][4];
  const f32x4 z = {0.0f, 0.0f, 0.0f, 0.0f};
  short8 wfc[4], wfn[4];

  auto zeroAcc = [&]() {
#pragma unroll
    for (int bt = 0; bt < 4; ++bt)
#pragma unroll
      for (int mt = 0; mt < 4; ++mt) acc[bt][mt] = z;
  };
  auto computeTile = [&]() {
#pragma unroll
    for (int ch = 0; ch < 4; ++ch) {
#pragma unroll
      for (int kk = 0; kk < 2; ++kk) {
        if (kk == 0)      loadW(ch, 1, wfn);      // weight prefetch, next kk
        else if (ch < 3)  loadW(ch + 1, 0, wfn);  // weight prefetch, next chunk
        const int koff = kk * 32 + qq * 8;
#pragma unroll
        for (int bt = 0; bt < 4; ++bt) {
          short8 af = *(const short8*)&Blds[ch][bt * 16 + cc][koff];
#pragma unroll
          for (int mt = 0; mt < 4; ++mt)
            acc[bt][mt] = __builtin_amdgcn_mfma_f32_16x16x32_bf16(af, wfc[mt],
                                                                  acc[bt][mt], 0, 0, 0);
        }
#pragma unroll
        for (int mt = 0; mt < 4; ++mt) wfc[mt] = wfn[mt];
      }
    }
  };

  // bias rows identical for both tiles -> load once
  const int mrow0 = kb * 256 + m0;
  float bv[4];
#pragma unroll
  for (int mt = 0; mt < 4; ++mt) {
    if constexpr (BF) bv[mt] = bf2f((unsigned short)bias[mrow0 + mt * 16 + cc]);
    else              bv[mt] = bias[mrow0 + mt * 16 + cc];
  }

  auto storeTile = [&](int tb) {
#pragma unroll
    for (int mt = 0; mt < 4; ++mt) {
      const size_t rowoff = (size_t)(mrow0 + mt * 16 + cc) * BCOLS;
#pragma unroll
      for (int bt = 0; bt < 4; ++bt) {
        f32x4 v = acc[bt][mt];
        const size_t o = rowoff + tb + bt * 16 + qq * 4;
        if constexpr (BF) {
          ushort4v p = {f2bf(v[0] + bv[mt]), f2bf(v[1] + bv[mt]),
                        f2bf(v[2] + bv[mt]), f2bf(v[3] + bv[mt])};
          *(ushort4v*)(out + o) = p;
        } else {
          float4 p = {v[0] + bv[mt], v[1] + bv[mt], v[2] + bv[mt], v[3] + bv[mt]};
          *(float4*)(out + o) = p;
        }
      }
    }
  };

  // ---- TILE A ----
  loadStageAll(b0);                      // 32 loads upfront
  __builtin_amdgcn_sched_barrier(0);
  loadW(0, 0, wfc);
#pragma unroll
  for (int mt = 0; mt < 4; ++mt) wfn[mt] = wfc[mt];
  writeStageAll();                       // counted vmcnt: waits A-loads only
  loadStageAll(b0 + 64);                 // TILE B loads in flight from here on
  __builtin_amdgcn_sched_barrier(0);
  bar_nodrain();                         // LDS-A visible; B-loads NOT drained
  zeroAcc();
  computeTile();                         // compute A (B-loads in flight)

  // ---- boundary: stores A overlap B-loads / B-compute ----
  storeTile(b0);                         // 16 stores, fire-and-forget
  __builtin_amdgcn_sched_barrier(0);
  loadW(0, 0, wfc);                      // W-frag for tile B (L2-hot)
#pragma unroll
  for (int mt = 0; mt < 4; ++mt) wfn[mt] = wfc[mt];
  bar_nodrain();                         // WAR: all waves done reading LDS-A
  writeStageAll();                       // vmcnt(16): waits B-loads, A-stores fly
  bar_nodrain();                         // LDS-B visible
  zeroAcc();
  computeTile();                         // compute B; A-stores drain beneath
  storeTile(b0 + 64);
}

template <bool WBF>
__global__ __launch_bounds__(256, 2) void BlockLinear_90752658965115_kernel(
    const void* __restrict__ inp, const void* __restrict__ blocks,
    const void* __restrict__ bias, const unsigned short* __restrict__ wbf,
    void* __restrict__ out) {
  __shared__ __align__(16) unsigned short Blds[4][64][72];  // 36 KiB
  if (detect_bf16(inp)) {
    run_bl<unsigned short, WBF>((const unsigned short*)inp,
                                (const unsigned short*)blocks, wbf,
                                (const unsigned short*)bias,
                                (unsigned short*)out, Blds);
  } else {
    run_bl<float, WBF>((const float*)inp, (const float*)blocks, wbf,
                       (const float*)bias, (float*)out, Blds);
  }
}

extern "C" void kernel_launch(void* const* d_in, const int* in_sizes, int n_in,
                              void* d_out, int out_size, void* d_ws, size_t ws_size,
                              hipStream_t stream) {
  (void)in_sizes; (void)n_in; (void)out_size;
  const size_t wbytes = (size_t)8 * 256 * 256 * 2;  // 1 MiB bf16 weights
  if (ws_size >= wbytes) {
    bl_convw<<<dim3(512), dim3(256), 0, stream>>>(d_in[1], (unsigned short*)d_ws);
    BlockLinear_90752658965115_kernel<true><<<dim3(512), dim3(256), 0, stream>>>(
        d_in[0], d_in[1], d_in[2], (unsigned short*)d_ws, d_out);
  } else {
    BlockLinear_90752658965115_kernel<false><<<dim3(512), dim3(256), 0, stream>>>(
        d_in[0], d_in[1], d_in[2], nullptr, d_out);
  }
}